// Round 11
// baseline (1661.106 us; speedup 1.0000x reference)
//
#include <hip/hip_runtime.h>
#include <hip/hip_bf16.h>

// B=64 graphs, N=512 pts, F0=6, K=8, conv out C=256, hidden H=336,
// m1 in 1030 (pad->1056), head 256->128->3.  fp32 in/out.
// Edge MLPs: bf16 MFMA, fp32 accum, wave-split-N + M=4 register blocking.
// R8: xi-factorization (P = xi@W1a per point). R9: B-frag reg prefetch.
// R10: XCD graph-locality swizzle. R11: memory diet — P stored bf16 and
// read via non-temporal loads (P streaming was evicting xfl from the 4MB
// per-XCD L2), xcat written/read non-temporally (stream-once data).

#define DEVFN __device__ __forceinline__
DEVFN float lrelu(float v) { return v >= 0.f ? v : 0.01f * v; }

using bf16x8 = __attribute__((ext_vector_type(8))) short;
using f32x4  = __attribute__((ext_vector_type(4))) float;
using u64x2  = __attribute__((ext_vector_type(2))) unsigned long long;

template<int N> struct IC { static constexpr int value = N; };

DEVFN unsigned short f2bf(float v) {
    __hip_bfloat16 h = __float2bfloat16(v);
    return *(unsigned short*)&h;
}
DEVFN float bf2f(unsigned short u) {
    return __uint_as_float((unsigned)u << 16);
}

// ---------------------------------------------------------------------------
// weight packing: fp32 [K][N] -> bf16 B-fragment layout [kt][nt][lane][8]
// mode 0: plain, rows >= Ksrc zero (W2s)
// mode 1: diff rows: k<p1 -> src[k]-src[k+p1]; else p0<=k<p0+p1 -> src[k-p0+p1]
// mode 2: m1 W1: k<6 -> src[k]; 32<=k -> src[k-26]; else 0
// mode 3: plain with row offset p0: src[k+p0]
// ---------------------------------------------------------------------------
struct PDesc { const float* src; unsigned short* dst; int Kt, NT, N, mode, p0, p1, Ksrc; };
struct PTable { PDesc d[13]; };

__global__ __launch_bounds__(256) void pack_kernel(PTable tb) {
    PDesc d = tb.d[blockIdx.y];
    int i = blockIdx.x * 256 + threadIdx.x;
    int tot = d.Kt * d.NT * 512;
    if (i >= tot) return;
    int j = i & 7, lane = (i >> 3) & 63;
    int tile = i >> 9;
    int nt = tile % d.NT, kt = tile / d.NT;
    int k = kt * 32 + ((lane >> 4) << 3) + j;
    int n = nt * 16 + (lane & 15);
    float v = 0.f;
    if (d.mode == 0) {
        if (k < d.Ksrc) v = d.src[(size_t)k * d.N + n];
    } else if (d.mode == 1) {
        if (k < d.p1) v = d.src[(size_t)k * d.N + n] - d.src[(size_t)(k + d.p1) * d.N + n];
        else if (k >= d.p0 && k < d.p0 + d.p1) v = d.src[(size_t)(k - d.p0 + d.p1) * d.N + n];
    } else if (d.mode == 2) {
        if (k < 6) v = d.src[(size_t)k * d.N + n];
        else if (k >= 32 && k < 1056) v = d.src[(size_t)(k - 26) * d.N + n];
    } else {
        v = d.src[(size_t)(k + d.p0) * d.N + n];
    }
    d.dst[i] = f2bf(v);
}

// ---------------------------------------------------------------------------
__global__ __launch_bounds__(256) void xbprep_kernel(const float* __restrict__ xb,
                                                     unsigned short* __restrict__ xbbf,
                                                     unsigned short* __restrict__ xcat) {
    int p = blockIdx.x * 256 + threadIdx.x;
    if (p >= 32768) return;
    unsigned short r[16];
    #pragma unroll
    for (int c = 0; c < 6; ++c) r[c] = f2bf(xb[p * 6 + c]);
    #pragma unroll
    for (int c = 6; c < 16; ++c) r[c] = 0;
    #pragma unroll
    for (int c = 0; c < 16; ++c) xbbf[p * 16 + c] = r[c];
    unsigned short* xc = xcat + (size_t)p * 1056;
    #pragma unroll
    for (int c = 0; c < 16; ++c) xc[c] = r[c];
    #pragma unroll
    for (int c = 16; c < 32; ++c) xc[c] = 0;
}

// ---------------------------------------------------------------------------
template<int F>
__global__ __launch_bounds__(256) void norms_kernel(const float* __restrict__ f,
                                                    float* __restrict__ nrm) {
    int p = blockIdx.x * 256 + threadIdx.x;
    if (p >= 64 * 512) return;
    const float* r = f + (size_t)p * F;
    float s = 0.f;
    #pragma unroll
    for (int i = 0; i < F; ++i) s += r[i] * r[i];
    nrm[p] = s;
}

// ---------------------------------------------------------------------------
// kNN fp32 (layer 1, F=6): 32 queries/block, stable top-8
// ---------------------------------------------------------------------------
template<int F>
__global__ __launch_bounds__(256) void knn_kernel(const float* __restrict__ feat,
                                                  const float* __restrict__ nrm,
                                                  int* __restrict__ knn) {
    constexpr int FP = (F == 6) ? 8 : (F + 4);
    __shared__ float Xq[32 * FP];
    __shared__ float Xc[32 * FP];
    __shared__ float qn[32], cn[32];
    __shared__ float dt[32 * 33];
    const int t  = threadIdx.x;
    const int b  = blockIdx.x >> 4;
    const int n0 = (blockIdx.x & 15) << 5;
    const float* fg = feat + (size_t)b * 512 * F;

    for (int i = t; i < 32 * F; i += 256) {
        int r = i / F, c = i - r * F;
        Xq[r * FP + c] = fg[(size_t)(n0 + r) * F + c];
    }
    if (t < 32) qn[t] = nrm[b * 512 + n0 + t];

    float d8[8]; int i8[8];
    #pragma unroll
    for (int k = 0; k < 8; ++k) { d8[k] = 3.4e38f; i8[k] = 0; }

    const int q = t >> 3, cs = t & 7;

    for (int ct = 0; ct < 16; ++ct) {
        const int c0 = ct << 5;
        __syncthreads();
        for (int i = t; i < 32 * F; i += 256) {
            int r = i / F, c = i - r * F;
            Xc[r * FP + c] = fg[(size_t)(c0 + r) * F + c];
        }
        if (t < 32) cn[t] = nrm[b * 512 + c0 + t];
        __syncthreads();

        float acc[4] = {0.f, 0.f, 0.f, 0.f};
        #pragma unroll
        for (int f = 0; f < F; ++f) {
            float qv = Xq[q * FP + f];
            #pragma unroll
            for (int j = 0; j < 4; ++j) acc[j] += qv * Xc[(cs + 8 * j) * FP + f];
        }
        #pragma unroll
        for (int j = 0; j < 4; ++j)
            dt[q * 33 + cs + 8 * j] = qn[q] + cn[cs + 8 * j] - 2.f * acc[j];
        __syncthreads();

        if (t < 32) {
            #pragma unroll 1
            for (int i = 0; i < 32; ++i) {
                float d = dt[t * 33 + i];
                if (d < d8[7]) {
                    d8[7] = d; i8[7] = c0 + i;
                    #pragma unroll
                    for (int s = 7; s >= 1; --s) {
                        if (d8[s] < d8[s - 1]) {
                            float td = d8[s]; d8[s] = d8[s - 1]; d8[s - 1] = td;
                            int   ti = i8[s]; i8[s] = i8[s - 1]; i8[s - 1] = ti;
                        }
                    }
                }
            }
        }
    }
    if (t < 32) {
        #pragma unroll
        for (int k = 0; k < 8; ++k)
            knn[((size_t)b * 512 + n0 + t) * 8 + k] = i8[k];
    }
}

// ---------------------------------------------------------------------------
// kNN via MFMA Gram (bf16x3), layers 2-4. Reads xfl (hi|lo, stride 512).
// 512 blocks = 8 xcd x 8 graphs x 8 query-strips (XCD swizzle).
// ---------------------------------------------------------------------------
__global__ __launch_bounds__(256, 2)
void knn_mfma(const unsigned short* __restrict__ xfl,
              const float* __restrict__ nrm,
              int* __restrict__ knn) {
    __shared__ unsigned short Qh[64 * 72], Ql[64 * 72], Ch[64 * 72], Cl[64 * 72];
    __shared__ float dt[64 * 66];
    __shared__ float qn[64], cn[64];
    float* mD = dt;
    int*   mI = (int*)(dt + 2048);

    const int t  = threadIdx.x;
    const int l  = t & 63, w = t >> 6;
    const int m16 = l & 15, q4 = l >> 4;
    const int bx = blockIdx.x;
    const int slot = bx >> 3;
    const int b  = (bx & 7) + 8 * (slot >> 3);   // graph: all its blocks on one XCD
    const int qs = (slot & 7) << 6;

    if (t < 64) qn[t] = nrm[b * 512 + qs + t];

    float d8[8]; int i8[8];
    #pragma unroll
    for (int k = 0; k < 8; ++k) { d8[k] = 3.4e38f; i8[k] = 0x7fffffff; }

    const int sr = t >> 2;
    const int sc = (t & 3) << 4;
    const int tq = t & 63, sub = t >> 6;

    for (int cs = 0; cs < 8; ++cs) {
        const int c0 = cs << 6;
        if (t < 64) cn[t] = nrm[b * 512 + c0 + t];

        f32x4 acc[4];
        #pragma unroll
        for (int i = 0; i < 4; ++i) acc[i] = (f32x4){0.f, 0.f, 0.f, 0.f};

        for (int kc = 0; kc < 4; ++kc) {
            const int k0 = kc << 6;
            __syncthreads();
            {
                const unsigned short* qr = xfl + (size_t)(b * 512 + qs + sr) * 512;
                const unsigned short* cr = xfl + (size_t)(b * 512 + c0 + sr) * 512;
                *(uint4*)&Qh[sr * 72 + sc]     = *(const uint4*)(qr + k0 + sc);
                *(uint4*)&Qh[sr * 72 + sc + 8] = *(const uint4*)(qr + k0 + sc + 8);
                *(uint4*)&Ql[sr * 72 + sc]     = *(const uint4*)(qr + 256 + k0 + sc);
                *(uint4*)&Ql[sr * 72 + sc + 8] = *(const uint4*)(qr + 256 + k0 + sc + 8);
                *(uint4*)&Ch[sr * 72 + sc]     = *(const uint4*)(cr + k0 + sc);
                *(uint4*)&Ch[sr * 72 + sc + 8] = *(const uint4*)(cr + k0 + sc + 8);
                *(uint4*)&Cl[sr * 72 + sc]     = *(const uint4*)(cr + 256 + k0 + sc);
                *(uint4*)&Cl[sr * 72 + sc + 8] = *(const uint4*)(cr + 256 + k0 + sc + 8);
            }
            __syncthreads();

            #pragma unroll
            for (int kt = 0; kt < 2; ++kt) {
                const int ko = kt * 32 + q4 * 8;
                bf16x8 ah = *(const bf16x8*)&Qh[(w * 16 + m16) * 72 + ko];
                bf16x8 al = *(const bf16x8*)&Ql[(w * 16 + m16) * 72 + ko];
                #pragma unroll
                for (int nt = 0; nt < 4; ++nt) {
                    bf16x8 bh = *(const bf16x8*)&Ch[(nt * 16 + m16) * 72 + ko];
                    bf16x8 bl = *(const bf16x8*)&Cl[(nt * 16 + m16) * 72 + ko];
                    acc[nt] = __builtin_amdgcn_mfma_f32_16x16x32_bf16(ah, bh, acc[nt], 0, 0, 0);
                    acc[nt] = __builtin_amdgcn_mfma_f32_16x16x32_bf16(ah, bl, acc[nt], 0, 0, 0);
                    acc[nt] = __builtin_amdgcn_mfma_f32_16x16x32_bf16(al, bh, acc[nt], 0, 0, 0);
                }
            }
        }

        #pragma unroll
        for (int nt = 0; nt < 4; ++nt) {
            float cv = cn[nt * 16 + m16];
            #pragma unroll
            for (int rr = 0; rr < 4; ++rr) {
                int qr = w * 16 + q4 * 4 + rr;
                dt[qr * 66 + nt * 16 + m16] = qn[qr] + cv - 2.f * acc[nt][rr];
            }
        }
        __syncthreads();

        {
            const float* drow = &dt[tq * 66 + sub * 16];
            #pragma unroll 1
            for (int j = 0; j < 16; ++j) {
                float d = drow[j];
                if (d < d8[7]) {
                    d8[7] = d; i8[7] = c0 + sub * 16 + j;
                    #pragma unroll
                    for (int s = 7; s >= 1; --s) {
                        if (d8[s] < d8[s - 1]) {
                            float td = d8[s]; d8[s] = d8[s - 1]; d8[s - 1] = td;
                            int   ti = i8[s]; i8[s] = i8[s - 1]; i8[s - 1] = ti;
                        }
                    }
                }
            }
        }
        __syncthreads();
    }

    #pragma unroll
    for (int k = 0; k < 8; ++k) {
        mD[(tq * 4 + sub) * 8 + k] = d8[k];
        mI[(tq * 4 + sub) * 8 + k] = i8[k];
    }
    __syncthreads();
    if (t < 64) {
        int p[4] = {0, 0, 0, 0};
        int outb = (b * 512 + qs + t) * 8;
        #pragma unroll 1
        for (int k = 0; k < 8; ++k) {
            float bd = 3.5e38f; int bi = 0x7fffffff; int bs = 0;
            #pragma unroll
            for (int s = 0; s < 4; ++s) {
                if (p[s] < 8) {
                    float dd = mD[(t * 4 + s) * 8 + p[s]];
                    int   ii = mI[(t * 4 + s) * 8 + p[s]];
                    if (dd < bd || (dd == bd && ii < bi)) { bd = dd; bi = ii; bs = s; }
                }
            }
            knn[outb + k] = bi;
            p[bs]++;
        }
    }
}

// ---------------------------------------------------------------------------
// Point-GEMM: P = x_hi @ W1a  (32768 x 336, K=256), 64 points/block.
// Output bf16; LDS-staged, fully contiguous 43KB/block stores.
// 512 blocks = 8 xcd x 8 graphs x 8 point-strips (XCD swizzle).
// ---------------------------------------------------------------------------
__global__ __launch_bounds__(256, 3)
void pgemm_kernel(const unsigned short* __restrict__ xfl,
                  const unsigned short* __restrict__ W1ap,
                  unsigned short* __restrict__ Pp) {
    __shared__ unsigned short smem[64 * 344];   // A-chunk (stride 264) / P-stage (stride 344)
    const int t = threadIdx.x;
    const int l = t & 63, w = t >> 6;
    const int q4 = l >> 4, m16 = l & 15;
    const int s1 = w * 6;
    const int bx = blockIdx.x;
    const int slot = bx >> 3;
    const int r0 = ((bx & 7) + 8 * (slot >> 3)) * 512 + (slot & 7) * 64;

    {
        const int r = t >> 2;
        const unsigned short* srow = xfl + (size_t)(r0 + r) * 512;
        #pragma unroll
        for (int s = 0; s < 8; ++s) {
            int c16 = (t & 3) + (s << 2);
            *(uint4*)&smem[r * 264 + c16 * 8] = *(const uint4*)(srow + c16 * 8);
        }
    }
    __syncthreads();

    f32x4 acc[4][6];
    #pragma unroll
    for (int mt = 0; mt < 4; ++mt)
        #pragma unroll
        for (int n = 0; n < 6; ++n) acc[mt][n] = (f32x4){0.f, 0.f, 0.f, 0.f};

    auto run = [&](auto c1c) {
        constexpr int C1 = decltype(c1c)::value;
        bf16x8 bcur[C1];
        {
            const unsigned short* bp = W1ap + ((size_t)s1 * 64 + l) * 8;
            #pragma unroll
            for (int n = 0; n < C1; ++n) bcur[n] = *(const bf16x8*)(bp + n * 512);
        }
        #pragma unroll 1
        for (int kt = 0; kt < 8; ++kt) {
            bf16x8 bnext[C1];
            if (kt + 1 < 8) {
                const unsigned short* bp = W1ap + ((size_t)((kt + 1) * 21 + s1) * 64 + l) * 8;
                #pragma unroll
                for (int n = 0; n < C1; ++n) bnext[n] = *(const bf16x8*)(bp + n * 512);
            }
            bf16x8 af[4];
            #pragma unroll
            for (int mt = 0; mt < 4; ++mt)
                af[mt] = *(const bf16x8*)&smem[(mt * 16 + m16) * 264 + q4 * 8 + kt * 32];
            #pragma unroll
            for (int n = 0; n < C1; ++n)
                #pragma unroll
                for (int mt = 0; mt < 4; ++mt)
                    acc[mt][n] = __builtin_amdgcn_mfma_f32_16x16x32_bf16(af[mt], bcur[n], acc[mt][n], 0, 0, 0);
            #pragma unroll
            for (int n = 0; n < C1; ++n) bcur[n] = bnext[n];
        }
    };
    if (w < 3) run(IC<6>{});
    else       run(IC<3>{});

    // stage bf16 P into LDS [64][344] then contiguous uint4 stores
    __syncthreads();
    {
        const int c1 = (w < 3) ? 6 : 3;
        for (int n = 0; n < c1; ++n) {
            int col = (s1 + n) * 16 + m16;
            #pragma unroll
            for (int mt = 0; mt < 4; ++mt)
                #pragma unroll
                for (int r = 0; r < 4; ++r)
                    smem[(mt * 16 + q4 * 4 + r) * 344 + col] = f2bf(acc[mt][n][r]);
        }
    }
    __syncthreads();
    {
        uint4* dst = (uint4*)(Pp + (size_t)r0 * 336);
        const uint4* src = (const uint4*)smem;
        #pragma unroll 1
        for (int i = t; i < 2688; i += 256)         // 64 rows x 42 uint4
            dst[i] = src[(i / 42) * 43 + (i % 42)]; // LDS stride 344 sh = 43 uint4
    }
}

// ---------------------------------------------------------------------------
// MFMA fused 2-layer MLP, wave-split-N, M=4 register blocking, B prefetch.
// MODE 0: conv F=256, GEMM1 = xj@W1b only; P (bf16) added via NT loads.
// MODE 1: conv1 (K=32 stacked [xi|xj]). MODE 2: m1 (K=1056, NT A loads).
// xcat written with NT stores (stream-once; keep xfl cached for next layer).
// ---------------------------------------------------------------------------
template<int MODE>
__global__ __launch_bounds__(256, 3)
void mfma_mlp(const unsigned short* __restrict__ featbf,
              const int* __restrict__ knn,
              const unsigned short* __restrict__ W1p, const float* __restrict__ B1,
              const unsigned short* __restrict__ W2p, const float* __restrict__ B2,
              const unsigned short* __restrict__ Pp,
              float* __restrict__ outf,
              unsigned short* __restrict__ xcat, int sliceoff,
              unsigned short* __restrict__ xfl, float* __restrict__ nrm) {
    constexpr int NCHUNK  = (MODE == 2) ? 3 : 1;
    constexpr int KTPC    = (MODE == 0) ? 8 : (MODE == 1) ? 1 : 11;
    constexpr int ASTRIDE = (MODE == 0) ? 264 : (MODE == 1) ? 40 : 360;

    __shared__ unsigned short smem[64 * 360];
    __shared__ int rowi[64];
    __shared__ int rowj[64];
    __shared__ float nparts[8][4];

    const int t = threadIdx.x;
    const int l = t & 63, w = t >> 6;
    const int q4 = l >> 4, m16 = l & 15;
    const int s1 = w * 6;          // GEMM1 ntile start (21 total: 6,6,6,3)
    const int s2 = w * 4;          // GEMM2 ntile start (16 total)

    // XCD swizzle: all blocks of a graph share blockIdx%8 -> same XCD L2
    const int bx = blockIdx.x;
    int p0;                         // first point (MODE 0/1) or row (MODE 2)
    if constexpr (MODE != 2) {
        int slot = bx >> 3;                      // 0..511
        int g = (bx & 7) + 8 * (slot >> 6);      // graph 0..63
        p0 = g * 512 + (slot & 63) * 8;          // 8 points/block
    } else {
        int slot = bx >> 3;                      // 0..63
        int g = (bx & 7) + 8 * (slot >> 3);      // graph 0..63
        p0 = g * 512 + (slot & 7) * 64;          // 64 rows/block
    }

    if (MODE != 2 && t < 64) {
        int pt = p0 + (t >> 3);
        rowi[t] = pt;
        rowj[t] = (pt & ~511) + knn[pt * 8 + (t & 7)];
    }

    f32x4 acc1[4][6];
    #pragma unroll
    for (int mt = 0; mt < 4; ++mt)
        #pragma unroll
        for (int n = 0; n < 6; ++n) acc1[mt][n] = (f32x4){0.f, 0.f, 0.f, 0.f};

    // GEMM1 over one staged chunk with register B double-buffer
    auto g1 = [&](auto c1c, int ktbase) {
        constexpr int C1 = decltype(c1c)::value;
        bf16x8 bcur[C1];
        {
            const unsigned short* bp =
                W1p + ((size_t)(ktbase * 21 + s1) * 64 + l) * 8;
            #pragma unroll
            for (int n = 0; n < C1; ++n) bcur[n] = *(const bf16x8*)(bp + n * 512);
        }
        #pragma unroll 1
        for (int kt = 0; kt < KTPC; ++kt) {
            bf16x8 bnext[C1];
            if (kt + 1 < KTPC) {
                const unsigned short* bp =
                    W1p + ((size_t)((ktbase + kt + 1) * 21 + s1) * 64 + l) * 8;
                #pragma unroll
                for (int n = 0; n < C1; ++n) bnext[n] = *(const bf16x8*)(bp + n * 512);
            }
            bf16x8 af[4];
            #pragma unroll
            for (int mt = 0; mt < 4; ++mt)
                af[mt] = *(const bf16x8*)&smem[(mt * 16 + m16) * ASTRIDE + q4 * 8 + kt * 32];
            #pragma unroll
            for (int n = 0; n < C1; ++n)
                #pragma unroll
                for (int mt = 0; mt < 4; ++mt)
                    acc1[mt][n] = __builtin_amdgcn_mfma_f32_16x16x32_bf16(af[mt], bcur[n], acc1[mt][n], 0, 0, 0);
            #pragma unroll
            for (int n = 0; n < C1; ++n) bcur[n] = bnext[n];
        }
    };

    for (int kc = 0; kc < NCHUNK; ++kc) {
        __syncthreads();
        if constexpr (MODE == 0) {
            const int r = t >> 2;
            const unsigned short* srow = featbf + (size_t)rowj[r] * 512;
            #pragma unroll
            for (int s = 0; s < 8; ++s) {
                int c16 = (t & 3) + (s << 2);
                *(uint4*)&smem[r * 264 + c16 * 8] = *(const uint4*)(srow + c16 * 8);
            }
        } else if constexpr (MODE == 1) {
            const int r = t >> 2, c16 = t & 3;
            const unsigned short* s2p =
                featbf + (size_t)(c16 < 2 ? rowi[r] : rowj[r]) * 16 + (c16 & 1) * 8;
            *(uint4*)&smem[r * 40 + c16 * 8] = *(const uint4*)s2p;
        } else {
            const int r = t >> 2;
            const unsigned short* srow =
                featbf + (size_t)(p0 + r) * 1056 + kc * 352;
            #pragma unroll
            for (int s = 0; s < 11; ++s) {
                int c16 = (t & 3) + (s << 2);
                u64x2 v = __builtin_nontemporal_load((const u64x2*)(srow + c16 * 8));
                *(u64x2*)&smem[r * 360 + c16 * 8] = v;
            }
        }
        __syncthreads();

        if (w < 3) g1(IC<6>{}, kc * KTPC);
        else       g1(IC<3>{}, kc * KTPC);
    }
    __syncthreads();

    // h1 = lrelu(acc1 [+ P] + b1) -> bf16 LDS [64][360]; cols 336..351 zeroed
    {
        const int c1 = (w < 3) ? 6 : 3;
        for (int n = 0; n < c1; ++n) {
            int nt = s1 + n;
            float b = B1[nt * 16 + m16];
            #pragma unroll
            for (int mt = 0; mt < 4; ++mt) {
                float pv = 0.f;
                if constexpr (MODE == 0) {
                    int prow = p0 + mt * 2 + (q4 >> 1);
                    pv = bf2f(__builtin_nontemporal_load(
                        &Pp[(size_t)prow * 336 + nt * 16 + m16]));
                }
                #pragma unroll
                for (int r = 0; r < 4; ++r) {
                    int row = mt * 16 + q4 * 4 + r;
                    float v = acc1[mt][n][r] + b + pv;
                    smem[row * 360 + nt * 16 + m16] = f2bf(lrelu(v));
                }
            }
        }
    }
    if (t < 64) {
        #pragma unroll
        for (int c = 336; c < 352; ++c) smem[t * 360 + c] = 0;
    }
    __syncthreads();

    // GEMM2: h1[64][352] x W2 slice (4 ntiles per wave), B prefetch
    f32x4 acc2[4][4];
    #pragma unroll
    for (int mt = 0; mt < 4; ++mt)
        #pragma unroll
        for (int n = 0; n < 4; ++n) acc2[mt][n] = (f32x4){0.f, 0.f, 0.f, 0.f};
    {
        bf16x8 bcur[4];
        {
            const unsigned short* bp = W2p + ((size_t)s2 * 64 + l) * 8;
            #pragma unroll
            for (int n = 0; n < 4; ++n) bcur[n] = *(const bf16x8*)(bp + n * 512);
        }
        #pragma unroll 1
        for (int kt = 0; kt < 11; ++kt) {
            bf16x8 bnext[4];
            if (kt + 1 < 11) {
                const unsigned short* bp = W2p + ((size_t)((kt + 1) * 16 + s2) * 64 + l) * 8;
                #pragma unroll
                for (int n = 0; n < 4; ++n) bnext[n] = *(const bf16x8*)(bp + n * 512);
            }
            bf16x8 af[4];
            #pragma unroll
            for (int mt = 0; mt < 4; ++mt)
                af[mt] = *(const bf16x8*)&smem[(mt * 16 + m16) * 360 + q4 * 8 + kt * 32];
            #pragma unroll
            for (int n = 0; n < 4; ++n)
                #pragma unroll
                for (int mt = 0; mt < 4; ++mt)
                    acc2[mt][n] = __builtin_amdgcn_mfma_f32_16x16x32_bf16(af[mt], bcur[n], acc2[mt][n], 0, 0, 0);
            #pragma unroll
            for (int n = 0; n < 4; ++n) bcur[n] = bnext[n];
        }
    }

    if constexpr (MODE != 2) {
        // max over 8 edges -> stage hi|lo into LDS, then coalesced stores
        __syncthreads();
        unsigned short* sh = smem;          // [8][512]: 0..255 hi, 256..511 lo
        #pragma unroll
        for (int mt = 0; mt < 4; ++mt) {
            float nsum = 0.f;
            int plocal = mt * 2 + (q4 >> 1);
            #pragma unroll
            for (int n = 0; n < 4; ++n) {
                int nt = s2 + n;
                float b = B2[nt * 16 + m16];
                float mv = -3.4e38f;
                #pragma unroll
                for (int r = 0; r < 4; ++r) mv = fmaxf(mv, lrelu(acc2[mt][n][r] + b));
                mv = fmaxf(mv, __shfl_xor(mv, 16, 64));
                if ((q4 & 1) == 0) {
                    int col = nt * 16 + m16;
                    unsigned short hi = f2bf(mv);
                    float fhi = bf2f(hi);
                    unsigned short lo = f2bf(mv - fhi);
                    float xr = fhi + bf2f(lo);
                    nsum += xr * xr;
                    sh[plocal * 512 + col] = hi;
                    sh[plocal * 512 + 256 + col] = lo;
                }
            }
            #pragma unroll
            for (int o = 1; o < 16; o <<= 1) nsum += __shfl_xor(nsum, o, 64);
            if ((q4 & 1) == 0 && m16 == 0) nparts[plocal][w] = nsum;
        }
        __syncthreads();
        {
            int r = t >> 5, cb = (t & 31) * 16;
            int p = p0 + r;
            uint4 v0 = *(uint4*)&sh[r * 512 + cb];
            uint4 v1 = *(uint4*)&sh[r * 512 + cb + 8];
            *(uint4*)&xfl[(size_t)p * 512 + cb]     = v0;       // cached: reused next layer
            *(uint4*)&xfl[(size_t)p * 512 + cb + 8] = v1;
            if (cb < 256) {                                      // NT: read only by m1
                __builtin_nontemporal_store(*(const u64x2*)&v0,
                    (u64x2*)&xcat[(size_t)p * 1056 + sliceoff + cb]);
                __builtin_nontemporal_store(*(const u64x2*)&v1,
                    (u64x2*)&xcat[(size_t)p * 1056 + sliceoff + cb + 8]);
            }
        }
        if (t < 8)
            nrm[p0 + t] =
                nparts[t][0] + nparts[t][1] + nparts[t][2] + nparts[t][3];
    } else {
        #pragma unroll
        for (int mt = 0; mt < 4; ++mt)
            #pragma unroll
            for (int n = 0; n < 4; ++n) {
                int nt = s2 + n;
                float b = B2[nt * 16 + m16];
                int col = nt * 16 + m16;
                #pragma unroll
                for (int r = 0; r < 4; ++r) {
                    int p = p0 + mt * 16 + q4 * 4 + r;
                    outf[(size_t)p * 256 + col] = lrelu(acc2[mt][n][r] + b);
                }
            }
    }
}

// ---------------------------------------------------------------------------
__global__ __launch_bounds__(256) void pool_kernel(const float* __restrict__ h,
                                                   float* __restrict__ g) {
    int b = blockIdx.x, t = threadIdx.x;
    const float* hb = h + (size_t)b * 512 * 256;
    float s = 0.f;
    for (int n = 0; n < 512; ++n) s += hb[n * 256 + t];
    g[b * 256 + t] = s * (1.f / 512.f);
}

__global__ __launch_bounds__(128) void head_kernel(const float* __restrict__ g,
                                                   const float* __restrict__ w1,
                                                   const float* __restrict__ b1,
                                                   const float* __restrict__ w2,
                                                   const float* __restrict__ b2,
                                                   float* __restrict__ out) {
    __shared__ float gs[256];
    __shared__ float hid[128];
    int b = blockIdx.x, t = threadIdx.x;
    gs[t] = g[b * 256 + t];
    gs[t + 128] = g[b * 256 + t + 128];
    __syncthreads();
    float s = b1[t];
    for (int c = 0; c < 256; ++c) s += gs[c] * w1[c * 128 + t];
    hid[t] = lrelu(s);
    __syncthreads();
    if (t < 3) {
        float o = b2[t];
        for (int j = 0; j < 128; ++j) o += hid[j] * w2[j * 3 + t];
        out[b * 3 + t] = o;
    }
}

// ---------------------------------------------------------------------------
extern "C" void kernel_launch(void* const* d_in, const int* in_sizes, int n_in,
                              void* d_out, int out_size, void* d_ws, size_t ws_size,
                              hipStream_t stream) {
    const float* xb = (const float*)d_in[0];
    const float* c_w1[4] = { (const float*)d_in[3],  (const float*)d_in[7],
                             (const float*)d_in[11], (const float*)d_in[15] };
    const float* c_b1[4] = { (const float*)d_in[4],  (const float*)d_in[8],
                             (const float*)d_in[12], (const float*)d_in[16] };
    const float* c_w2[4] = { (const float*)d_in[5],  (const float*)d_in[9],
                             (const float*)d_in[13], (const float*)d_in[17] };
    const float* c_b2[4] = { (const float*)d_in[6],  (const float*)d_in[10],
                             (const float*)d_in[14], (const float*)d_in[18] };
    const float* m1w1 = (const float*)d_in[19];
    const float* m1b1 = (const float*)d_in[20];
    const float* m1w2 = (const float*)d_in[21];
    const float* m1b2 = (const float*)d_in[22];
    const float* m2w1 = (const float*)d_in[23];
    const float* m2b1 = (const float*)d_in[24];
    const float* m2w2 = (const float*)d_in[25];
    const float* m2b2 = (const float*)d_in[26];

    char* base = (char*)d_ws;
    size_t off = 0;
    auto alloc = [&](size_t bytes) { char* p = base + off; off = (off + bytes + 255) & ~(size_t)255; return p; };
    int*            knn   = (int*)           alloc((size_t)32768 * 8 * 4);
    float*          nrm   = (float*)         alloc((size_t)32768 * 4);
    char*           Preg  =                  alloc((size_t)32768 * 256 * 4); // union: P bf16 (22MB) / hm fp32 (33.5MB)
    float*          g     = (float*)         alloc(64 * 256 * 4);
    unsigned short* xcat  = (unsigned short*)alloc((size_t)32768 * 1056 * 2);
    unsigned short* xfl   = (unsigned short*)alloc((size_t)32768 * 512 * 2);
    unsigned short* xbbf  = (unsigned short*)alloc((size_t)32768 * 16 * 2);
    unsigned short* w1p1  = (unsigned short*)alloc((size_t)1  * 21 * 512 * 2);
    unsigned short* w2p1  = (unsigned short*)alloc((size_t)11 * 16 * 512 * 2);
    unsigned short* w1a[3]; unsigned short* w1b[3]; unsigned short* w2p[3];
    for (int i = 0; i < 3; ++i) {
        w1a[i] = (unsigned short*)alloc((size_t)8  * 21 * 512 * 2);
        w1b[i] = (unsigned short*)alloc((size_t)8  * 21 * 512 * 2);
        w2p[i] = (unsigned short*)alloc((size_t)11 * 16 * 512 * 2);
    }
    unsigned short* m1p1  = (unsigned short*)alloc((size_t)33 * 21 * 512 * 2);
    unsigned short* m1p2  = (unsigned short*)alloc((size_t)11 * 16 * 512 * 2);
    unsigned short* Pp = (unsigned short*)Preg;  // bf16 P
    float*          hm = (float*)Preg;           // m1 output reuses region (P dead)

    PTable tb;
    tb.d[0] = { c_w1[0], w1p1, 1,  21, 336, 1, 16,  6,   0   };
    tb.d[1] = { c_w2[0], w2p1, 11, 16, 256, 0, 0,   0,   336 };
    for (int i = 0; i < 3; ++i) {
        tb.d[2 + 3 * i] = { c_w1[i + 1], w1a[i], 8,  21, 336, 1, 0,   256, 0   };
        tb.d[3 + 3 * i] = { c_w1[i + 1], w1b[i], 8,  21, 336, 3, 256, 0,   0   };
        tb.d[4 + 3 * i] = { c_w2[i + 1], w2p[i], 11, 16, 256, 0, 0,   0,   336 };
    }
    tb.d[11] = { m1w1, m1p1, 33, 21, 336, 2, 0, 0, 0   };
    tb.d[12] = { m1w2, m1p2, 11, 16, 256, 0, 0, 0, 336 };
    pack_kernel<<<dim3(1386, 13), dim3(256), 0, stream>>>(tb);
    xbprep_kernel<<<128, 256, 0, stream>>>(xb, xbbf, xcat);

    // layer 1 (F=6): fp32 kNN on xb, conv1 writes xfl/xcat-slice/norm of x1
    norms_kernel<6><<<128, 256, 0, stream>>>(xb, nrm);
    knn_kernel<6><<<1024, 256, 0, stream>>>(xb, nrm, knn);
    mfma_mlp<1><<<4096, 256, 0, stream>>>(xbbf, knn,
                                          w1p1, c_b1[0], w2p1, c_b2[0], nullptr,
                                          nullptr, xcat, 32, xfl, nrm);

    // layers 2..4: MFMA kNN + point-GEMM + conv
    for (int l = 1; l < 4; ++l) {
        int dstslice = 32 + l * 256;
        knn_mfma<<<512, 256, 0, stream>>>(xfl, nrm, knn);
        pgemm_kernel<<<512, 256, 0, stream>>>(xfl, w1a[l - 1], Pp);
        mfma_mlp<0><<<4096, 256, 0, stream>>>(xfl, knn,
                                              w1b[l - 1], c_b1[l], w2p[l - 1], c_b2[l], Pp,
                                              nullptr, xcat, dstslice, xfl, nrm);
    }

    // m1 over Xcat (hm aliases P region — P is dead now)
    mfma_mlp<2><<<512, 256, 0, stream>>>(xcat, nullptr,
                                         m1p1, m1b1, m1p2, m1b2, nullptr,
                                         hm, nullptr, 0, nullptr, nullptr);

    pool_kernel<<<64, 256, 0, stream>>>(hm, g);
    head_kernel<<<64, 128, 0, stream>>>(g, m2w1, m2b1, m2w2, m2b2, (float*)d_out);
}

// Round 12
// 1451.574 us; speedup vs baseline: 1.1443x; 1.1443x over previous
//
#include <hip/hip_runtime.h>
#include <hip/hip_bf16.h>

// B=64 graphs, N=512 pts, F0=6, K=8, conv out C=256, hidden H=336,
// m1 in 1030 (pad->1056), head 256->128->3.  fp32 in/out.
// Edge MLPs: bf16 MFMA, fp32 accum, wave-split-N + M=4 register blocking.
// R8: xi-factorization (P = xi@W1a per point). R9: B-frag reg prefetch.
// R10: XCD graph-locality swizzle. R12: P in bf16 with CACHED loads
// (R11's non-temporal intrinsics regressed 13% — NT bypasses L2 retention
// and turned cheap L2-hit epilogue loads into full-latency transactions).

#define DEVFN __device__ __forceinline__
DEVFN float lrelu(float v) { return v >= 0.f ? v : 0.01f * v; }

using bf16x8 = __attribute__((ext_vector_type(8))) short;
using f32x4  = __attribute__((ext_vector_type(4))) float;

template<int N> struct IC { static constexpr int value = N; };

DEVFN unsigned short f2bf(float v) {
    __hip_bfloat16 h = __float2bfloat16(v);
    return *(unsigned short*)&h;
}
DEVFN float bf2f(unsigned short u) {
    return __uint_as_float((unsigned)u << 16);
}

// ---------------------------------------------------------------------------
// weight packing: fp32 [K][N] -> bf16 B-fragment layout [kt][nt][lane][8]
// mode 0: plain, rows >= Ksrc zero (W2s)
// mode 1: diff rows: k<p1 -> src[k]-src[k+p1]; else p0<=k<p0+p1 -> src[k-p0+p1]
// mode 2: m1 W1: k<6 -> src[k]; 32<=k -> src[k-26]; else 0
// mode 3: plain with row offset p0: src[k+p0]
// ---------------------------------------------------------------------------
struct PDesc { const float* src; unsigned short* dst; int Kt, NT, N, mode, p0, p1, Ksrc; };
struct PTable { PDesc d[13]; };

__global__ __launch_bounds__(256) void pack_kernel(PTable tb) {
    PDesc d = tb.d[blockIdx.y];
    int i = blockIdx.x * 256 + threadIdx.x;
    int tot = d.Kt * d.NT * 512;
    if (i >= tot) return;
    int j = i & 7, lane = (i >> 3) & 63;
    int tile = i >> 9;
    int nt = tile % d.NT, kt = tile / d.NT;
    int k = kt * 32 + ((lane >> 4) << 3) + j;
    int n = nt * 16 + (lane & 15);
    float v = 0.f;
    if (d.mode == 0) {
        if (k < d.Ksrc) v = d.src[(size_t)k * d.N + n];
    } else if (d.mode == 1) {
        if (k < d.p1) v = d.src[(size_t)k * d.N + n] - d.src[(size_t)(k + d.p1) * d.N + n];
        else if (k >= d.p0 && k < d.p0 + d.p1) v = d.src[(size_t)(k - d.p0 + d.p1) * d.N + n];
    } else if (d.mode == 2) {
        if (k < 6) v = d.src[(size_t)k * d.N + n];
        else if (k >= 32 && k < 1056) v = d.src[(size_t)(k - 26) * d.N + n];
    } else {
        v = d.src[(size_t)(k + d.p0) * d.N + n];
    }
    d.dst[i] = f2bf(v);
}

// ---------------------------------------------------------------------------
__global__ __launch_bounds__(256) void xbprep_kernel(const float* __restrict__ xb,
                                                     unsigned short* __restrict__ xbbf,
                                                     unsigned short* __restrict__ xcat) {
    int p = blockIdx.x * 256 + threadIdx.x;
    if (p >= 32768) return;
    unsigned short r[16];
    #pragma unroll
    for (int c = 0; c < 6; ++c) r[c] = f2bf(xb[p * 6 + c]);
    #pragma unroll
    for (int c = 6; c < 16; ++c) r[c] = 0;
    #pragma unroll
    for (int c = 0; c < 16; ++c) xbbf[p * 16 + c] = r[c];
    unsigned short* xc = xcat + (size_t)p * 1056;
    #pragma unroll
    for (int c = 0; c < 16; ++c) xc[c] = r[c];
    #pragma unroll
    for (int c = 16; c < 32; ++c) xc[c] = 0;
}

// ---------------------------------------------------------------------------
template<int F>
__global__ __launch_bounds__(256) void norms_kernel(const float* __restrict__ f,
                                                    float* __restrict__ nrm) {
    int p = blockIdx.x * 256 + threadIdx.x;
    if (p >= 64 * 512) return;
    const float* r = f + (size_t)p * F;
    float s = 0.f;
    #pragma unroll
    for (int i = 0; i < F; ++i) s += r[i] * r[i];
    nrm[p] = s;
}

// ---------------------------------------------------------------------------
// kNN fp32 (layer 1, F=6): 32 queries/block, stable top-8
// ---------------------------------------------------------------------------
template<int F>
__global__ __launch_bounds__(256) void knn_kernel(const float* __restrict__ feat,
                                                  const float* __restrict__ nrm,
                                                  int* __restrict__ knn) {
    constexpr int FP = (F == 6) ? 8 : (F + 4);
    __shared__ float Xq[32 * FP];
    __shared__ float Xc[32 * FP];
    __shared__ float qn[32], cn[32];
    __shared__ float dt[32 * 33];
    const int t  = threadIdx.x;
    const int b  = blockIdx.x >> 4;
    const int n0 = (blockIdx.x & 15) << 5;
    const float* fg = feat + (size_t)b * 512 * F;

    for (int i = t; i < 32 * F; i += 256) {
        int r = i / F, c = i - r * F;
        Xq[r * FP + c] = fg[(size_t)(n0 + r) * F + c];
    }
    if (t < 32) qn[t] = nrm[b * 512 + n0 + t];

    float d8[8]; int i8[8];
    #pragma unroll
    for (int k = 0; k < 8; ++k) { d8[k] = 3.4e38f; i8[k] = 0; }

    const int q = t >> 3, cs = t & 7;

    for (int ct = 0; ct < 16; ++ct) {
        const int c0 = ct << 5;
        __syncthreads();
        for (int i = t; i < 32 * F; i += 256) {
            int r = i / F, c = i - r * F;
            Xc[r * FP + c] = fg[(size_t)(c0 + r) * F + c];
        }
        if (t < 32) cn[t] = nrm[b * 512 + c0 + t];
        __syncthreads();

        float acc[4] = {0.f, 0.f, 0.f, 0.f};
        #pragma unroll
        for (int f = 0; f < F; ++f) {
            float qv = Xq[q * FP + f];
            #pragma unroll
            for (int j = 0; j < 4; ++j) acc[j] += qv * Xc[(cs + 8 * j) * FP + f];
        }
        #pragma unroll
        for (int j = 0; j < 4; ++j)
            dt[q * 33 + cs + 8 * j] = qn[q] + cn[cs + 8 * j] - 2.f * acc[j];
        __syncthreads();

        if (t < 32) {
            #pragma unroll 1
            for (int i = 0; i < 32; ++i) {
                float d = dt[t * 33 + i];
                if (d < d8[7]) {
                    d8[7] = d; i8[7] = c0 + i;
                    #pragma unroll
                    for (int s = 7; s >= 1; --s) {
                        if (d8[s] < d8[s - 1]) {
                            float td = d8[s]; d8[s] = d8[s - 1]; d8[s - 1] = td;
                            int   ti = i8[s]; i8[s] = i8[s - 1]; i8[s - 1] = ti;
                        }
                    }
                }
            }
        }
    }
    if (t < 32) {
        #pragma unroll
        for (int k = 0; k < 8; ++k)
            knn[((size_t)b * 512 + n0 + t) * 8 + k] = i8[k];
    }
}

// ---------------------------------------------------------------------------
// kNN via MFMA Gram (bf16x3), layers 2-4. Reads xfl (hi|lo, stride 512).
// 512 blocks = 8 xcd x 8 graphs x 8 query-strips (XCD swizzle).
// ---------------------------------------------------------------------------
__global__ __launch_bounds__(256, 2)
void knn_mfma(const unsigned short* __restrict__ xfl,
              const float* __restrict__ nrm,
              int* __restrict__ knn) {
    __shared__ unsigned short Qh[64 * 72], Ql[64 * 72], Ch[64 * 72], Cl[64 * 72];
    __shared__ float dt[64 * 66];
    __shared__ float qn[64], cn[64];
    float* mD = dt;
    int*   mI = (int*)(dt + 2048);

    const int t  = threadIdx.x;
    const int l  = t & 63, w = t >> 6;
    const int m16 = l & 15, q4 = l >> 4;
    const int bx = blockIdx.x;
    const int slot = bx >> 3;
    const int b  = (bx & 7) + 8 * (slot >> 3);   // graph: all its blocks on one XCD
    const int qs = (slot & 7) << 6;

    if (t < 64) qn[t] = nrm[b * 512 + qs + t];

    float d8[8]; int i8[8];
    #pragma unroll
    for (int k = 0; k < 8; ++k) { d8[k] = 3.4e38f; i8[k] = 0x7fffffff; }

    const int sr = t >> 2;
    const int sc = (t & 3) << 4;
    const int tq = t & 63, sub = t >> 6;

    for (int cs = 0; cs < 8; ++cs) {
        const int c0 = cs << 6;
        if (t < 64) cn[t] = nrm[b * 512 + c0 + t];

        f32x4 acc[4];
        #pragma unroll
        for (int i = 0; i < 4; ++i) acc[i] = (f32x4){0.f, 0.f, 0.f, 0.f};

        for (int kc = 0; kc < 4; ++kc) {
            const int k0 = kc << 6;
            __syncthreads();
            {
                const unsigned short* qr = xfl + (size_t)(b * 512 + qs + sr) * 512;
                const unsigned short* cr = xfl + (size_t)(b * 512 + c0 + sr) * 512;
                *(uint4*)&Qh[sr * 72 + sc]     = *(const uint4*)(qr + k0 + sc);
                *(uint4*)&Qh[sr * 72 + sc + 8] = *(const uint4*)(qr + k0 + sc + 8);
                *(uint4*)&Ql[sr * 72 + sc]     = *(const uint4*)(qr + 256 + k0 + sc);
                *(uint4*)&Ql[sr * 72 + sc + 8] = *(const uint4*)(qr + 256 + k0 + sc + 8);
                *(uint4*)&Ch[sr * 72 + sc]     = *(const uint4*)(cr + k0 + sc);
                *(uint4*)&Ch[sr * 72 + sc + 8] = *(const uint4*)(cr + k0 + sc + 8);
                *(uint4*)&Cl[sr * 72 + sc]     = *(const uint4*)(cr + 256 + k0 + sc);
                *(uint4*)&Cl[sr * 72 + sc + 8] = *(const uint4*)(cr + 256 + k0 + sc + 8);
            }
            __syncthreads();

            #pragma unroll
            for (int kt = 0; kt < 2; ++kt) {
                const int ko = kt * 32 + q4 * 8;
                bf16x8 ah = *(const bf16x8*)&Qh[(w * 16 + m16) * 72 + ko];
                bf16x8 al = *(const bf16x8*)&Ql[(w * 16 + m16) * 72 + ko];
                #pragma unroll
                for (int nt = 0; nt < 4; ++nt) {
                    bf16x8 bh = *(const bf16x8*)&Ch[(nt * 16 + m16) * 72 + ko];
                    bf16x8 bl = *(const bf16x8*)&Cl[(nt * 16 + m16) * 72 + ko];
                    acc[nt] = __builtin_amdgcn_mfma_f32_16x16x32_bf16(ah, bh, acc[nt], 0, 0, 0);
                    acc[nt] = __builtin_amdgcn_mfma_f32_16x16x32_bf16(ah, bl, acc[nt], 0, 0, 0);
                    acc[nt] = __builtin_amdgcn_mfma_f32_16x16x32_bf16(al, bh, acc[nt], 0, 0, 0);
                }
            }
        }

        #pragma unroll
        for (int nt = 0; nt < 4; ++nt) {
            float cv = cn[nt * 16 + m16];
            #pragma unroll
            for (int rr = 0; rr < 4; ++rr) {
                int qr = w * 16 + q4 * 4 + rr;
                dt[qr * 66 + nt * 16 + m16] = qn[qr] + cv - 2.f * acc[nt][rr];
            }
        }
        __syncthreads();

        {
            const float* drow = &dt[tq * 66 + sub * 16];
            #pragma unroll 1
            for (int j = 0; j < 16; ++j) {
                float d = drow[j];
                if (d < d8[7]) {
                    d8[7] = d; i8[7] = c0 + sub * 16 + j;
                    #pragma unroll
                    for (int s = 7; s >= 1; --s) {
                        if (d8[s] < d8[s - 1]) {
                            float td = d8[s]; d8[s] = d8[s - 1]; d8[s - 1] = td;
                            int   ti = i8[s]; i8[s] = i8[s - 1]; i8[s - 1] = ti;
                        }
                    }
                }
            }
        }
        __syncthreads();
    }

    #pragma unroll
    for (int k = 0; k < 8; ++k) {
        mD[(tq * 4 + sub) * 8 + k] = d8[k];
        mI[(tq * 4 + sub) * 8 + k] = i8[k];
    }
    __syncthreads();
    if (t < 64) {
        int p[4] = {0, 0, 0, 0};
        int outb = (b * 512 + qs + t) * 8;
        #pragma unroll 1
        for (int k = 0; k < 8; ++k) {
            float bd = 3.5e38f; int bi = 0x7fffffff; int bs = 0;
            #pragma unroll
            for (int s = 0; s < 4; ++s) {
                if (p[s] < 8) {
                    float dd = mD[(t * 4 + s) * 8 + p[s]];
                    int   ii = mI[(t * 4 + s) * 8 + p[s]];
                    if (dd < bd || (dd == bd && ii < bi)) { bd = dd; bi = ii; bs = s; }
                }
            }
            knn[outb + k] = bi;
            p[bs]++;
        }
    }
}

// ---------------------------------------------------------------------------
// Point-GEMM: P = x_hi @ W1a  (32768 x 336, K=256), 64 points/block.
// Output bf16; LDS-staged, fully contiguous stores.
// 512 blocks = 8 xcd x 8 graphs x 8 point-strips (XCD swizzle).
// ---------------------------------------------------------------------------
__global__ __launch_bounds__(256, 3)
void pgemm_kernel(const unsigned short* __restrict__ xfl,
                  const unsigned short* __restrict__ W1ap,
                  unsigned short* __restrict__ Pp) {
    __shared__ unsigned short smem[64 * 344];   // A-chunk (stride 264) / P-stage (stride 344)
    const int t = threadIdx.x;
    const int l = t & 63, w = t >> 6;
    const int q4 = l >> 4, m16 = l & 15;
    const int s1 = w * 6;
    const int bx = blockIdx.x;
    const int slot = bx >> 3;
    const int r0 = ((bx & 7) + 8 * (slot >> 3)) * 512 + (slot & 7) * 64;

    {
        const int r = t >> 2;
        const unsigned short* srow = xfl + (size_t)(r0 + r) * 512;
        #pragma unroll
        for (int s = 0; s < 8; ++s) {
            int c16 = (t & 3) + (s << 2);
            *(uint4*)&smem[r * 264 + c16 * 8] = *(const uint4*)(srow + c16 * 8);
        }
    }
    __syncthreads();

    f32x4 acc[4][6];
    #pragma unroll
    for (int mt = 0; mt < 4; ++mt)
        #pragma unroll
        for (int n = 0; n < 6; ++n) acc[mt][n] = (f32x4){0.f, 0.f, 0.f, 0.f};

    auto run = [&](auto c1c) {
        constexpr int C1 = decltype(c1c)::value;
        bf16x8 bcur[C1];
        {
            const unsigned short* bp = W1ap + ((size_t)s1 * 64 + l) * 8;
            #pragma unroll
            for (int n = 0; n < C1; ++n) bcur[n] = *(const bf16x8*)(bp + n * 512);
        }
        #pragma unroll 1
        for (int kt = 0; kt < 8; ++kt) {
            bf16x8 bnext[C1];
            if (kt + 1 < 8) {
                const unsigned short* bp = W1ap + ((size_t)((kt + 1) * 21 + s1) * 64 + l) * 8;
                #pragma unroll
                for (int n = 0; n < C1; ++n) bnext[n] = *(const bf16x8*)(bp + n * 512);
            }
            bf16x8 af[4];
            #pragma unroll
            for (int mt = 0; mt < 4; ++mt)
                af[mt] = *(const bf16x8*)&smem[(mt * 16 + m16) * 264 + q4 * 8 + kt * 32];
            #pragma unroll
            for (int n = 0; n < C1; ++n)
                #pragma unroll
                for (int mt = 0; mt < 4; ++mt)
                    acc[mt][n] = __builtin_amdgcn_mfma_f32_16x16x32_bf16(af[mt], bcur[n], acc[mt][n], 0, 0, 0);
            #pragma unroll
            for (int n = 0; n < C1; ++n) bcur[n] = bnext[n];
        }
    };
    if (w < 3) run(IC<6>{});
    else       run(IC<3>{});

    // stage bf16 P into LDS [64][344] then contiguous uint4 stores
    __syncthreads();
    {
        const int c1 = (w < 3) ? 6 : 3;
        for (int n = 0; n < c1; ++n) {
            int col = (s1 + n) * 16 + m16;
            #pragma unroll
            for (int mt = 0; mt < 4; ++mt)
                #pragma unroll
                for (int r = 0; r < 4; ++r)
                    smem[(mt * 16 + q4 * 4 + r) * 344 + col] = f2bf(acc[mt][n][r]);
        }
    }
    __syncthreads();
    {
        uint4* dst = (uint4*)(Pp + (size_t)r0 * 336);
        const uint4* src = (const uint4*)smem;
        #pragma unroll 1
        for (int i = t; i < 2688; i += 256)         // 64 rows x 42 uint4
            dst[i] = src[(i / 42) * 43 + (i % 42)]; // LDS stride 344 sh = 43 uint4
    }
}

// ---------------------------------------------------------------------------
// MFMA fused 2-layer MLP, wave-split-N, M=4 register blocking, B prefetch.
// MODE 0: conv F=256, GEMM1 = xj@W1b only; P (bf16) added via cached loads.
// MODE 1: conv1 (K=32 stacked [xi|xj]). MODE 2: m1 (K=1056), fp32 out, no max.
// ---------------------------------------------------------------------------
template<int MODE>
__global__ __launch_bounds__(256, 3)
void mfma_mlp(const unsigned short* __restrict__ featbf,
              const int* __restrict__ knn,
              const unsigned short* __restrict__ W1p, const float* __restrict__ B1,
              const unsigned short* __restrict__ W2p, const float* __restrict__ B2,
              const unsigned short* __restrict__ Pp,
              float* __restrict__ outf,
              unsigned short* __restrict__ xcat, int sliceoff,
              unsigned short* __restrict__ xfl, float* __restrict__ nrm) {
    constexpr int NCHUNK  = (MODE == 2) ? 3 : 1;
    constexpr int KTPC    = (MODE == 0) ? 8 : (MODE == 1) ? 1 : 11;
    constexpr int ASTRIDE = (MODE == 0) ? 264 : (MODE == 1) ? 40 : 360;

    __shared__ unsigned short smem[64 * 360];
    __shared__ int rowi[64];
    __shared__ int rowj[64];
    __shared__ float nparts[8][4];

    const int t = threadIdx.x;
    const int l = t & 63, w = t >> 6;
    const int q4 = l >> 4, m16 = l & 15;
    const int s1 = w * 6;          // GEMM1 ntile start (21 total: 6,6,6,3)
    const int s2 = w * 4;          // GEMM2 ntile start (16 total)

    // XCD swizzle: all blocks of a graph share blockIdx%8 -> same XCD L2
    const int bx = blockIdx.x;
    int p0;                         // first point (MODE 0/1) or row (MODE 2)
    if constexpr (MODE != 2) {
        int slot = bx >> 3;                      // 0..511
        int g = (bx & 7) + 8 * (slot >> 6);      // graph 0..63
        p0 = g * 512 + (slot & 63) * 8;          // 8 points/block
    } else {
        int slot = bx >> 3;                      // 0..63
        int g = (bx & 7) + 8 * (slot >> 3);      // graph 0..63
        p0 = g * 512 + (slot & 7) * 64;          // 64 rows/block
    }

    if (MODE != 2 && t < 64) {
        int pt = p0 + (t >> 3);
        rowi[t] = pt;
        rowj[t] = (pt & ~511) + knn[pt * 8 + (t & 7)];
    }

    f32x4 acc1[4][6];
    #pragma unroll
    for (int mt = 0; mt < 4; ++mt)
        #pragma unroll
        for (int n = 0; n < 6; ++n) acc1[mt][n] = (f32x4){0.f, 0.f, 0.f, 0.f};

    // GEMM1 over one staged chunk with register B double-buffer
    auto g1 = [&](auto c1c, int ktbase) {
        constexpr int C1 = decltype(c1c)::value;
        bf16x8 bcur[C1];
        {
            const unsigned short* bp =
                W1p + ((size_t)(ktbase * 21 + s1) * 64 + l) * 8;
            #pragma unroll
            for (int n = 0; n < C1; ++n) bcur[n] = *(const bf16x8*)(bp + n * 512);
        }
        #pragma unroll 1
        for (int kt = 0; kt < KTPC; ++kt) {
            bf16x8 bnext[C1];
            if (kt + 1 < KTPC) {
                const unsigned short* bp =
                    W1p + ((size_t)((ktbase + kt + 1) * 21 + s1) * 64 + l) * 8;
                #pragma unroll
                for (int n = 0; n < C1; ++n) bnext[n] = *(const bf16x8*)(bp + n * 512);
            }
            bf16x8 af[4];
            #pragma unroll
            for (int mt = 0; mt < 4; ++mt)
                af[mt] = *(const bf16x8*)&smem[(mt * 16 + m16) * ASTRIDE + q4 * 8 + kt * 32];
            #pragma unroll
            for (int n = 0; n < C1; ++n)
                #pragma unroll
                for (int mt = 0; mt < 4; ++mt)
                    acc1[mt][n] = __builtin_amdgcn_mfma_f32_16x16x32_bf16(af[mt], bcur[n], acc1[mt][n], 0, 0, 0);
            #pragma unroll
            for (int n = 0; n < C1; ++n) bcur[n] = bnext[n];
        }
    };

    for (int kc = 0; kc < NCHUNK; ++kc) {
        __syncthreads();
        if constexpr (MODE == 0) {
            const int r = t >> 2;
            const unsigned short* srow = featbf + (size_t)rowj[r] * 512;
            #pragma unroll
            for (int s = 0; s < 8; ++s) {
                int c16 = (t & 3) + (s << 2);
                *(uint4*)&smem[r * 264 + c16 * 8] = *(const uint4*)(srow + c16 * 8);
            }
        } else if constexpr (MODE == 1) {
            const int r = t >> 2, c16 = t & 3;
            const unsigned short* s2p =
                featbf + (size_t)(c16 < 2 ? rowi[r] : rowj[r]) * 16 + (c16 & 1) * 8;
            *(uint4*)&smem[r * 40 + c16 * 8] = *(const uint4*)s2p;
        } else {
            const int r = t >> 2;
            const unsigned short* srow =
                featbf + (size_t)(p0 + r) * 1056 + kc * 352;
            #pragma unroll
            for (int s = 0; s < 11; ++s) {
                int c16 = (t & 3) + (s << 2);
                *(uint4*)&smem[r * 360 + c16 * 8] = *(const uint4*)(srow + c16 * 8);
            }
        }
        __syncthreads();

        if (w < 3) g1(IC<6>{}, kc * KTPC);
        else       g1(IC<3>{}, kc * KTPC);
    }
    __syncthreads();

    // h1 = lrelu(acc1 [+ P] + b1) -> bf16 LDS [64][360]; cols 336..351 zeroed
    {
        const int c1 = (w < 3) ? 6 : 3;
        for (int n = 0; n < c1; ++n) {
            int nt = s1 + n;
            float b = B1[nt * 16 + m16];
            #pragma unroll
            for (int mt = 0; mt < 4; ++mt) {
                float pv = 0.f;
                if constexpr (MODE == 0) {
                    int prow = p0 + mt * 2 + (q4 >> 1);
                    pv = bf2f(Pp[(size_t)prow * 336 + nt * 16 + m16]);
                }
                #pragma unroll
                for (int r = 0; r < 4; ++r) {
                    int row = mt * 16 + q4 * 4 + r;
                    float v = acc1[mt][n][r] + b + pv;
                    smem[row * 360 + nt * 16 + m16] = f2bf(lrelu(v));
                }
            }
        }
    }
    if (t < 64) {
        #pragma unroll
        for (int c = 336; c < 352; ++c) smem[t * 360 + c] = 0;
    }
    __syncthreads();

    // GEMM2: h1[64][352] x W2 slice (4 ntiles per wave), B prefetch
    f32x4 acc2[4][4];
    #pragma unroll
    for (int mt = 0; mt < 4; ++mt)
        #pragma unroll
        for (int n = 0; n < 4; ++n) acc2[mt][n] = (f32x4){0.f, 0.f, 0.f, 0.f};
    {
        bf16x8 bcur[4];
        {
            const unsigned short* bp = W2p + ((size_t)s2 * 64 + l) * 8;
            #pragma unroll
            for (int n = 0; n < 4; ++n) bcur[n] = *(const bf16x8*)(bp + n * 512);
        }
        #pragma unroll 1
        for (int kt = 0; kt < 11; ++kt) {
            bf16x8 bnext[4];
            if (kt + 1 < 11) {
                const unsigned short* bp = W2p + ((size_t)((kt + 1) * 16 + s2) * 64 + l) * 8;
                #pragma unroll
                for (int n = 0; n < 4; ++n) bnext[n] = *(const bf16x8*)(bp + n * 512);
            }
            bf16x8 af[4];
            #pragma unroll
            for (int mt = 0; mt < 4; ++mt)
                af[mt] = *(const bf16x8*)&smem[(mt * 16 + m16) * 360 + q4 * 8 + kt * 32];
            #pragma unroll
            for (int n = 0; n < 4; ++n)
                #pragma unroll
                for (int mt = 0; mt < 4; ++mt)
                    acc2[mt][n] = __builtin_amdgcn_mfma_f32_16x16x32_bf16(af[mt], bcur[n], acc2[mt][n], 0, 0, 0);
            #pragma unroll
            for (int n = 0; n < 4; ++n) bcur[n] = bnext[n];
        }
    }

    if constexpr (MODE != 2) {
        // max over 8 edges -> stage hi|lo into LDS, then coalesced stores
        __syncthreads();
        unsigned short* sh = smem;          // [8][512]: 0..255 hi, 256..511 lo
        #pragma unroll
        for (int mt = 0; mt < 4; ++mt) {
            float nsum = 0.f;
            int plocal = mt * 2 + (q4 >> 1);
            #pragma unroll
            for (int n = 0; n < 4; ++n) {
                int nt = s2 + n;
                float b = B2[nt * 16 + m16];
                float mv = -3.4e38f;
                #pragma unroll
                for (int r = 0; r < 4; ++r) mv = fmaxf(mv, lrelu(acc2[mt][n][r] + b));
                mv = fmaxf(mv, __shfl_xor(mv, 16, 64));
                if ((q4 & 1) == 0) {
                    int col = nt * 16 + m16;
                    unsigned short hi = f2bf(mv);
                    float fhi = bf2f(hi);
                    unsigned short lo = f2bf(mv - fhi);
                    float xr = fhi + bf2f(lo);
                    nsum += xr * xr;
                    sh[plocal * 512 + col] = hi;
                    sh[plocal * 512 + 256 + col] = lo;
                }
            }
            #pragma unroll
            for (int o = 1; o < 16; o <<= 1) nsum += __shfl_xor(nsum, o, 64);
            if ((q4 & 1) == 0 && m16 == 0) nparts[plocal][w] = nsum;
        }
        __syncthreads();
        {
            int r = t >> 5, cb = (t & 31) * 16;
            int p = p0 + r;
            uint4 v0 = *(uint4*)&sh[r * 512 + cb];
            uint4 v1 = *(uint4*)&sh[r * 512 + cb + 8];
            *(uint4*)&xfl[(size_t)p * 512 + cb]     = v0;
            *(uint4*)&xfl[(size_t)p * 512 + cb + 8] = v1;
            if (cb < 256) {
                *(uint4*)&xcat[(size_t)p * 1056 + sliceoff + cb]     = v0;
                *(uint4*)&xcat[(size_t)p * 1056 + sliceoff + cb + 8] = v1;
            }
        }
        if (t < 8)
            nrm[p0 + t] =
                nparts[t][0] + nparts[t][1] + nparts[t][2] + nparts[t][3];
    } else {
        #pragma unroll
        for (int mt = 0; mt < 4; ++mt)
            #pragma unroll
            for (int n = 0; n < 4; ++n) {
                int nt = s2 + n;
                float b = B2[nt * 16 + m16];
                int col = nt * 16 + m16;
                #pragma unroll
                for (int r = 0; r < 4; ++r) {
                    int p = p0 + mt * 16 + q4 * 4 + r;
                    outf[(size_t)p * 256 + col] = lrelu(acc2[mt][n][r] + b);
                }
            }
    }
}

// ---------------------------------------------------------------------------
__global__ __launch_bounds__(256) void pool_kernel(const float* __restrict__ h,
                                                   float* __restrict__ g) {
    int b = blockIdx.x, t = threadIdx.x;
    const float* hb = h + (size_t)b * 512 * 256;
    float s = 0.f;
    for (int n = 0; n < 512; ++n) s += hb[n * 256 + t];
    g[b * 256 + t] = s * (1.f / 512.f);
}

__global__ __launch_bounds__(128) void head_kernel(const float* __restrict__ g,
                                                   const float* __restrict__ w1,
                                                   const float* __restrict__ b1,
                                                   const float* __restrict__ w2,
                                                   const float* __restrict__ b2,
                                                   float* __restrict__ out) {
    __shared__ float gs[256];
    __shared__ float hid[128];
    int b = blockIdx.x, t = threadIdx.x;
    gs[t] = g[b * 256 + t];
    gs[t + 128] = g[b * 256 + t + 128];
    __syncthreads();
    float s = b1[t];
    for (int c = 0; c < 256; ++c) s += gs[c] * w1[c * 128 + t];
    hid[t] = lrelu(s);
    __syncthreads();
    if (t < 3) {
        float o = b2[t];
        for (int j = 0; j < 128; ++j) o += hid[j] * w2[j * 3 + t];
        out[b * 3 + t] = o;
    }
}

// ---------------------------------------------------------------------------
extern "C" void kernel_launch(void* const* d_in, const int* in_sizes, int n_in,
                              void* d_out, int out_size, void* d_ws, size_t ws_size,
                              hipStream_t stream) {
    const float* xb = (const float*)d_in[0];
    const float* c_w1[4] = { (const float*)d_in[3],  (const float*)d_in[7],
                             (const float*)d_in[11], (const float*)d_in[15] };
    const float* c_b1[4] = { (const float*)d_in[4],  (const float*)d_in[8],
                             (const float*)d_in[12], (const float*)d_in[16] };
    const float* c_w2[4] = { (const float*)d_in[5],  (const float*)d_in[9],
                             (const float*)d_in[13], (const float*)d_in[17] };
    const float* c_b2[4] = { (const float*)d_in[6],  (const float*)d_in[10],
                             (const float*)d_in[14], (const float*)d_in[18] };
    const float* m1w1 = (const float*)d_in[19];
    const float* m1b1 = (const float*)d_in[20];
    const float* m1w2 = (const float*)d_in[21];
    const float* m1b2 = (const float*)d_in[22];
    const float* m2w1 = (const float*)d_in[23];
    const float* m2b1 = (const float*)d_in[24];
    const float* m2w2 = (const float*)d_in[25];
    const float* m2b2 = (const float*)d_in[26];

    char* base = (char*)d_ws;
    size_t off = 0;
    auto alloc = [&](size_t bytes) { char* p = base + off; off = (off + bytes + 255) & ~(size_t)255; return p; };
    int*            knn   = (int*)           alloc((size_t)32768 * 8 * 4);
    float*          nrm   = (float*)         alloc((size_t)32768 * 4);
    char*           Preg  =                  alloc((size_t)32768 * 256 * 4); // union: P bf16 (22MB) / hm fp32 (33.5MB)
    float*          g     = (float*)         alloc(64 * 256 * 4);
    unsigned short* xcat  = (unsigned short*)alloc((size_t)32768 * 1056 * 2);
    unsigned short* xfl   = (unsigned short*)alloc((size_t)32768 * 512 * 2);
    unsigned short* xbbf  = (unsigned short*)alloc((size_t)32768 * 16 * 2);
    unsigned short* w1p1  = (unsigned short*)alloc((size_t)1  * 21 * 512 * 2);
    unsigned short* w2p1  = (unsigned short*)alloc((size_t)11 * 16 * 512 * 2);
    unsigned short* w1a[3]; unsigned short* w1b[3]; unsigned short* w2p[3];
    for (int i = 0; i < 3; ++i) {
        w1a[i] = (unsigned short*)alloc((size_t)8  * 21 * 512 * 2);
        w1b[i] = (unsigned short*)alloc((size_t)8  * 21 * 512 * 2);
        w2p[i] = (unsigned short*)alloc((size_t)11 * 16 * 512 * 2);
    }
    unsigned short* m1p1  = (unsigned short*)alloc((size_t)33 * 21 * 512 * 2);
    unsigned short* m1p2  = (unsigned short*)alloc((size_t)11 * 16 * 512 * 2);
    unsigned short* Pp = (unsigned short*)Preg;  // bf16 P
    float*          hm = (float*)Preg;           // m1 output reuses region (P dead)

    PTable tb;
    tb.d[0] = { c_w1[0], w1p1, 1,  21, 336, 1, 16,  6,   0   };
    tb.d[1] = { c_w2[0], w2p1, 11, 16, 256, 0, 0,   0,   336 };
    for (int i = 0; i < 3; ++i) {
        tb.d[2 + 3 * i] = { c_w1[i + 1], w1a[i], 8,  21, 336, 1, 0,   256, 0   };
        tb.d[3 + 3 * i] = { c_w1[i + 1], w1b[i], 8,  21, 336, 3, 256, 0,   0   };
        tb.d[4 + 3 * i] = { c_w2[i + 1], w2p[i], 11, 16, 256, 0, 0,   0,   336 };
    }
    tb.d[11] = { m1w1, m1p1, 33, 21, 336, 2, 0, 0, 0   };
    tb.d[12] = { m1w2, m1p2, 11, 16, 256, 0, 0, 0, 336 };
    pack_kernel<<<dim3(1386, 13), dim3(256), 0, stream>>>(tb);
    xbprep_kernel<<<128, 256, 0, stream>>>(xb, xbbf, xcat);

    // layer 1 (F=6): fp32 kNN on xb, conv1 writes xfl/xcat-slice/norm of x1
    norms_kernel<6><<<128, 256, 0, stream>>>(xb, nrm);
    knn_kernel<6><<<1024, 256, 0, stream>>>(xb, nrm, knn);
    mfma_mlp<1><<<4096, 256, 0, stream>>>(xbbf, knn,
                                          w1p1, c_b1[0], w2p1, c_b2[0], nullptr,
                                          nullptr, xcat, 32, xfl, nrm);

    // layers 2..4: MFMA kNN + point-GEMM + conv
    for (int l = 1; l < 4; ++l) {
        int dstslice = 32 + l * 256;
        knn_mfma<<<512, 256, 0, stream>>>(xfl, nrm, knn);
        pgemm_kernel<<<512, 256, 0, stream>>>(xfl, w1a[l - 1], Pp);
        mfma_mlp<0><<<4096, 256, 0, stream>>>(xfl, knn,
                                              w1b[l - 1], c_b1[l], w2p[l - 1], c_b2[l], Pp,
                                              nullptr, xcat, dstslice, xfl, nrm);
    }

    // m1 over Xcat (hm aliases P region — P is dead now)
    mfma_mlp<2><<<512, 256, 0, stream>>>(xcat, nullptr,
                                         m1p1, m1b1, m1p2, m1b2, nullptr,
                                         hm, nullptr, 0, nullptr, nullptr);

    pool_kernel<<<64, 256, 0, stream>>>(hm, g);
    head_kernel<<<64, 128, 0, stream>>>(g, m2w1, m2b1, m2w2, m2b2, (float*)d_out);
}